// Round 10
// baseline (102.071 us; speedup 1.0000x reference)
//
#include <hip/hip_runtime.h>

// Problem constants
#define S_   16384
#define T_   16384
#define B_   32
#define NEDGES (S_ * 64)       // 1,048,576
#define GP_  512               // producer blocks, 2048 edges each (32 sources)
#define EPG  2048              // edges per producer block
#define NBKT 256               // buckets of 64 targets
#define TPB  64                // targets per bucket
#define CAPT 128               // per-target LDS slots: mean 64, max ~104
#define OVF_CAP 64             // LDS overflow records (expected 0)
#define REG  5120              // per-bucket global region: mean 4096, +16 sigma
#define GOVF_CAP 1024          // global overflow records (expected 0)

// weight = clip(att,0,1) * 0.9^delay, delay in [0,6). Exact bit-product.
__device__ __forceinline__ float edge_weight(float a, int d) {
  float w = fminf(fmaxf(a, 0.0f), 1.0f);
  float r = (d & 1) ? 0.9f : 1.0f;
  r = (d & 2) ? r * 0.81f   : r;
  r = (d & 4) ? r * 0.6561f : r;
  return w * r;
}

// ---------------------------------------------------------------------------
// K1 (v10): per-bucket DENSE global regions. Block g: transpose 32 sources,
// LDS histogram of its 2048 edges over 256 buckets, reserve per-bucket runs
// via one device atomicAdd per bucket (gcur stride 64B to spread lines),
// direct scatter-write of records {tl<<14|src, w} into rec[bk*REG + slot].
// Deletes: LDS record buffer (16KB), scan, contiguous flush, ofse.
__global__ __launch_bounds__(512) void produce(
    const float* __restrict__ spikes,
    const float* __restrict__ att,
    const int*   __restrict__ tgt,
    const int*   __restrict__ del,
    float*        __restrict__ spikesT,
    int2*         __restrict__ rec,
    unsigned int* __restrict__ gcur,     // [NBKT*16 + 16], 64B-strided counters
    int2*         __restrict__ govf) {
  __shared__ float tile[32][33];        // 4.2 KB
  __shared__ int   cnt5[NBKT], cur5[NBKT], base5[NBKT];  // 3 KB

  const int g   = blockIdx.x;
  const int tid = threadIdx.x;
  if (tid < NBKT) { cnt5[tid] = 0; cur5[tid] = 0; }

  // -- transpose sources [g*32, g*32+32): load
  const int s0 = g * 32;
  {
    const int x = tid & 31, y = tid >> 5;       // y 0..15
    tile[x][y]      = spikes[(size_t)y        * S_ + s0 + x];
    tile[x][y + 16] = spikes[(size_t)(y + 16) * S_ + s0 + x];
  }

  // -- load my 4 edges (registers)
  const int e4  = g * 512 + tid;
  int4   t = reinterpret_cast<const int4*>(tgt)[e4];
  float4 a = reinterpret_cast<const float4*>(att)[e4];
  int4   d = reinterpret_cast<const int4*>(del)[e4];
  const int src = e4 >> 4;                      // (e4*4)>>6

  __syncthreads();                              // cnt init + tile visible

  // -- transpose write
  {
    const int b = tid & 31, j = tid >> 5;       // j 0..15
    spikesT[(size_t)(s0 + j)      * 32 + b] = tile[j][b];
    spikesT[(size_t)(s0 + j + 16) * 32 + b] = tile[j + 16][b];
  }

  // -- histogram (bucket = target >> 6)
  const int bk0 = t.x >> 6, bk1 = t.y >> 6, bk2 = t.z >> 6, bk3 = t.w >> 6;
  __hip_atomic_fetch_add(&cnt5[bk0], 1, __ATOMIC_RELAXED, __HIP_MEMORY_SCOPE_WORKGROUP);
  __hip_atomic_fetch_add(&cnt5[bk1], 1, __ATOMIC_RELAXED, __HIP_MEMORY_SCOPE_WORKGROUP);
  __hip_atomic_fetch_add(&cnt5[bk2], 1, __ATOMIC_RELAXED, __HIP_MEMORY_SCOPE_WORKGROUP);
  __hip_atomic_fetch_add(&cnt5[bk3], 1, __ATOMIC_RELAXED, __HIP_MEMORY_SCOPE_WORKGROUP);
  __syncthreads();

  // -- reserve dense runs: one device atomic per bucket per block
  if (tid < NBKT)
    base5[tid] = (int)__hip_atomic_fetch_add(&gcur[(size_t)tid * 16],
                                             (unsigned)cnt5[tid],
                                             __ATOMIC_RELAXED,
                                             __HIP_MEMORY_SCOPE_AGENT);
  __syncthreads();

  // -- place 4 records directly into global bucket regions
#define PUT(BK, TL, AV, DV)                                                   \
  {                                                                           \
    int p = __hip_atomic_fetch_add(&cur5[BK], 1, __ATOMIC_RELAXED,            \
                                   __HIP_MEMORY_SCOPE_WORKGROUP);             \
    const int slot = base5[BK] + p;                                           \
    const int wb = __float_as_int(edge_weight((AV), (DV)));                   \
    if (slot < REG) {                                                         \
      rec[(size_t)(BK) * REG + slot] = make_int2(((TL) << 14) | src, wb);     \
    } else {                                                                  \
      unsigned q = __hip_atomic_fetch_add(&gcur[(size_t)NBKT * 16], 1u,       \
                                          __ATOMIC_RELAXED,                   \
                                          __HIP_MEMORY_SCOPE_AGENT);          \
      if (q < GOVF_CAP)                                                       \
        govf[q] = make_int2(((BK) << 20) | ((TL) << 14) | src, wb);           \
    }                                                                         \
  }
  PUT(bk0, t.x & 63, a.x, d.x)
  PUT(bk1, t.y & 63, a.y, d.y)
  PUT(bk2, t.z & 63, a.z, d.z)
  PUT(bk3, t.w & 63, a.w, d.w)
#undef PUT
}

// ---------------------------------------------------------------------------
// K2 (v10): bucket k reads its DENSE region [0,n) fully coalesced (2x int4
// per thread), direct-places into fixed 128-slot per-target LDS slices,
// interleaved register gather (v9 structure). No sse/ofse bookkeeping.
__global__ __launch_bounds__(1024) void consume(
    const int2*  __restrict__ rec,
    const unsigned int* __restrict__ gcur,
    const int2*  __restrict__ govf,
    const float* __restrict__ spikesT,
    float* __restrict__ out) {
  __shared__ int2  srt[TPB * CAPT];     // 64 KB, target t owns [t*CAPT, ...)
  __shared__ float otile[TPB][33];      // 8.4 KB
  __shared__ int   cur64[TPB];
  __shared__ int2  lovf[OVF_CAP];
  __shared__ int   lovfn;

  const int k   = blockIdx.x;
  const int tid = threadIdx.x;
  const int b   = tid & 31;
  const int hw  = tid >> 5;             // 0..31

  if (tid < TPB) cur64[tid] = tid * CAPT;
  if (tid == 0)  lovfn = 0;
  __syncthreads();

  const int n = min((int)gcur[(size_t)k * 16], REG);
  const int2* myrec = rec + (size_t)k * REG;

#define PLACE(R)                                                              \
  {                                                                           \
    const int tl_ = ((R).x >> 14) & 63;                                       \
    int p_ = __hip_atomic_fetch_add(&cur64[tl_], 1, __ATOMIC_RELAXED,         \
                                    __HIP_MEMORY_SCOPE_WORKGROUP);            \
    if (p_ < (tl_ + 1) * CAPT) {                                              \
      srt[p_] = (R);                                                          \
    } else {                                                                  \
      int q_ = __hip_atomic_fetch_add(&lovfn, 1, __ATOMIC_RELAXED,            \
                                      __HIP_MEMORY_SCOPE_WORKGROUP);          \
      if (q_ < OVF_CAP) lovf[q_] = (R);                                       \
    }                                                                         \
  }

  // dense pass: 4 records per thread per sweep, fully coalesced
  for (int i0 = tid * 4; i0 + 4 <= n; i0 += 4096) {
    const int4* p4 = reinterpret_cast<const int4*>(myrec + i0);
    int4 x = p4[0], y = p4[1];
    int2 r0 = make_int2(x.x, x.y), r1 = make_int2(x.z, x.w);
    int2 r2 = make_int2(y.x, y.y), r3 = make_int2(y.z, y.w);
    PLACE(r0) PLACE(r1) PLACE(r2) PLACE(r3)
  }
  {
    const int base = n & ~3;
    const int idx  = base + tid;
    if (idx < n) { int2 r = myrec[idx]; PLACE(r) }
  }
  // global overflow (expected 0): thread 0 scans tiny list
  if (tid == 0) {
    int m = min((int)gcur[(size_t)NBKT * 16], GOVF_CAP);
    for (int j = 0; j < m; ++j) {
      int2 r = govf[j];
      if (((r.x >> 20) & 0xFF) == k) {
        int2 rr = make_int2(r.x & 0xFFFFF, r.y);
        PLACE(rr)
      }
    }
  }
#undef PLACE
  __syncthreads();

  // gather: half-wave hw owns targets hw (acc0) and hw+32 (acc1); lane=batch.
  float acc0 = 0.f, acc1 = 0.f;
  int e0 = hw * CAPT;
  int e1 = (hw + 32) * CAPT;
  const int e0e = min(cur64[hw],      (hw + 1)  * CAPT);
  const int e1e = min(cur64[hw + 32], (hw + 33) * CAPT);

  for (; e0 + 4 <= e0e && e1 + 4 <= e1e; e0 += 4, e1 += 4) {
    int2 r0 = srt[e0], r1 = srt[e0 + 1], r2 = srt[e0 + 2], r3 = srt[e0 + 3];
    int2 q0 = srt[e1], q1 = srt[e1 + 1], q2 = srt[e1 + 2], q3 = srt[e1 + 3];
    float s0 = spikesT[(size_t)(r0.x & 0x3FFF) * 32 + b];
    float s1 = spikesT[(size_t)(r1.x & 0x3FFF) * 32 + b];
    float s2 = spikesT[(size_t)(r2.x & 0x3FFF) * 32 + b];
    float s3 = spikesT[(size_t)(r3.x & 0x3FFF) * 32 + b];
    float u0 = spikesT[(size_t)(q0.x & 0x3FFF) * 32 + b];
    float u1 = spikesT[(size_t)(q1.x & 0x3FFF) * 32 + b];
    float u2 = spikesT[(size_t)(q2.x & 0x3FFF) * 32 + b];
    float u3 = spikesT[(size_t)(q3.x & 0x3FFF) * 32 + b];
    acc0 = fmaf(__int_as_float(r0.y), s0, acc0);
    acc0 = fmaf(__int_as_float(r1.y), s1, acc0);
    acc0 = fmaf(__int_as_float(r2.y), s2, acc0);
    acc0 = fmaf(__int_as_float(r3.y), s3, acc0);
    acc1 = fmaf(__int_as_float(q0.y), u0, acc1);
    acc1 = fmaf(__int_as_float(q1.y), u1, acc1);
    acc1 = fmaf(__int_as_float(q2.y), u2, acc1);
    acc1 = fmaf(__int_as_float(q3.y), u3, acc1);
  }
  for (; e0 + 4 <= e0e; e0 += 4) {
    int2 r0 = srt[e0], r1 = srt[e0 + 1], r2 = srt[e0 + 2], r3 = srt[e0 + 3];
    float s0 = spikesT[(size_t)(r0.x & 0x3FFF) * 32 + b];
    float s1 = spikesT[(size_t)(r1.x & 0x3FFF) * 32 + b];
    float s2 = spikesT[(size_t)(r2.x & 0x3FFF) * 32 + b];
    float s3 = spikesT[(size_t)(r3.x & 0x3FFF) * 32 + b];
    acc0 = fmaf(__int_as_float(r0.y), s0, acc0);
    acc0 = fmaf(__int_as_float(r1.y), s1, acc0);
    acc0 = fmaf(__int_as_float(r2.y), s2, acc0);
    acc0 = fmaf(__int_as_float(r3.y), s3, acc0);
  }
  for (; e0 < e0e; ++e0) {
    int2 r = srt[e0];
    acc0 = fmaf(__int_as_float(r.y), spikesT[(size_t)(r.x & 0x3FFF) * 32 + b], acc0);
  }
  for (; e1 + 4 <= e1e; e1 += 4) {
    int2 q0 = srt[e1], q1 = srt[e1 + 1], q2 = srt[e1 + 2], q3 = srt[e1 + 3];
    float u0 = spikesT[(size_t)(q0.x & 0x3FFF) * 32 + b];
    float u1 = spikesT[(size_t)(q1.x & 0x3FFF) * 32 + b];
    float u2 = spikesT[(size_t)(q2.x & 0x3FFF) * 32 + b];
    float u3 = spikesT[(size_t)(q3.x & 0x3FFF) * 32 + b];
    acc1 = fmaf(__int_as_float(q0.y), u0, acc1);
    acc1 = fmaf(__int_as_float(q1.y), u1, acc1);
    acc1 = fmaf(__int_as_float(q2.y), u2, acc1);
    acc1 = fmaf(__int_as_float(q3.y), u3, acc1);
  }
  for (; e1 < e1e; ++e1) {
    int2 q = srt[e1];
    acc1 = fmaf(__int_as_float(q.y), spikesT[(size_t)(q.x & 0x3FFF) * 32 + b], acc1);
  }

  // LDS overflow drain (expected empty)
  const int no = min(lovfn, OVF_CAP);
  for (int j = 0; j < no; ++j) {
    int2 r = lovf[j];
    const int tl = (r.x >> 14) & 63;
    float s = spikesT[(size_t)(r.x & 0x3FFF) * 32 + b];
    float w = __int_as_float(r.y);
    if (tl == hw)      acc0 = fmaf(w, s, acc0);
    if (tl == hw + 32) acc1 = fmaf(w, s, acc1);
  }

  // transpose 64x32 tile and write out coalesced
  otile[hw][b]      = acc0;
  otile[hw + 32][b] = acc1;
  __syncthreads();
  const int bb = tid >> 5;              // batch 0..31
  const int cc = (tid & 31) * 2;        // target pair 0..62
  float2 o2 = make_float2(otile[cc][bb], otile[cc + 1][bb]);
  *reinterpret_cast<float2*>(&out[(size_t)bb * T_ + k * 64 + cc]) = o2;
}

// ---------------------------------------------------------------------------
__global__ void zero_floats(float* __restrict__ p, int n) {
  int i = blockIdx.x * blockDim.x + threadIdx.x;
  if (i < n) p[i] = 0.0f;
}

// Emergency fallback (tiny ws): direct global atomics, weights inline.
__global__ void naive_kernel(const float* __restrict__ spikes,
                             const float* __restrict__ att,
                             const int*   __restrict__ tgt,
                             const int*   __restrict__ del,
                             float*       __restrict__ out) {
  int i = blockIdx.x * blockDim.x + threadIdx.x;
  if (i >= NEDGES) return;
  int   s = i >> 6;
  int   t = tgt[i];
  float w = edge_weight(att[i], del[i]);
  for (int b = 0; b < B_; ++b)
    unsafeAtomicAdd(&out[(size_t)b * T_ + t], w * spikes[(size_t)b * S_ + s]);
}

// ---------------------------------------------------------------------------
extern "C" void kernel_launch(void* const* d_in, const int* in_sizes, int n_in,
                              void* d_out, int out_size, void* d_ws, size_t ws_size,
                              hipStream_t stream) {
  const float* spikes = (const float*)d_in[0];
  const float* att    = (const float*)d_in[1];
  const int*   tgt    = (const int*)d_in[2];
  const int*   del    = (const int*)d_in[3];
  float*       out    = (float*)d_out;

  const size_t spikesT_bytes = (size_t)S_ * B_ * sizeof(float);           // 2 MB
  const size_t rec_bytes     = (size_t)NBKT * REG * sizeof(int2);         // 10 MB
  const size_t gcur_bytes    = ((size_t)NBKT * 16 + 16) * sizeof(unsigned); // 16.4 KB
  const size_t govf_bytes    = (size_t)GOVF_CAP * sizeof(int2);           // 8 KB
  const size_t need = spikesT_bytes + rec_bytes + gcur_bytes + govf_bytes + 64;

  if (ws_size < need) {
    zero_floats<<<(B_ * T_ + 255) / 256, 256, 0, stream>>>(out, B_ * T_);
    naive_kernel<<<(NEDGES + 255) / 256, 256, 0, stream>>>(spikes, att, tgt, del, out);
    return;
  }

  char* p = (char*)d_ws;
  float*        spikesT = (float*)p;        p += spikesT_bytes;
  int2*         rec     = (int2*)p;         p += rec_bytes;
  unsigned int* gcur    = (unsigned int*)p; p += gcur_bytes;
  int2*         govf    = (int2*)p;

  hipMemsetAsync(gcur, 0, gcur_bytes, stream);   // zero cursors + ovf count
  produce<<<GP_, 512, 0, stream>>>(spikes, att, tgt, del, spikesT, rec, gcur, govf);
  consume<<<NBKT, 1024, 0, stream>>>(rec, gcur, govf, spikesT, out);
}

// Round 11
// 87.814 us; speedup vs baseline: 1.1624x; 1.1624x over previous
//
#include <hip/hip_runtime.h>

// Problem constants
#define S_   16384
#define T_   16384
#define B_   32
#define NEDGES (S_ * 64)       // 1,048,576
#define GP_  256               // producer blocks, 4096 edges each
#define EPG  4096              // edges per producer block
#define NBKT 512               // buckets of 32 targets
#define TPB  32                // targets per bucket
#define CAPT 128               // per-target slots: mean 64, global max ~100
#define OVF_CAP 64             // overflow records (expected ~0)

// weight = clip(att,0,1) * 0.9^delay, delay in [0,6). Exact bit-product.
__device__ __forceinline__ float edge_weight(float a, int d) {
  float w = fminf(fmaxf(a, 0.0f), 1.0f);
  float r = (d & 1) ? 0.9f : 1.0f;
  r = (d & 2) ? r * 0.81f   : r;
  r = (d & 4) ? r * 0.6561f : r;
  return w * r;
}

// ---------------------------------------------------------------------------
// K1 (= verified v8): transpose 64 sources of spikes + LDS counting-sort of
// 4096 edges by bucket + ONE contiguous 32 KB flush. rec[g][i]: records
// {meta = tl<<14 | src, w_bits} grouped by bucket.
// ofse transposed: ofse[k*GP_ + g] = end<<16 | start (consume reads 1KB burst).
__global__ __launch_bounds__(1024) void produce(
    const float* __restrict__ spikes,
    const float* __restrict__ att,
    const int*   __restrict__ tgt,
    const int*   __restrict__ del,
    float*        __restrict__ spikesT,
    int2*         __restrict__ rec,
    unsigned int* __restrict__ ofse) {
  __shared__ float tile[64][33];        // 8.4 KB
  __shared__ int4  sbuf4[EPG / 2];      // 32 KB: 4096 int2 records
  __shared__ int   cnt5[NBKT], cur5[NBKT], sofs5[NBKT];
  __shared__ int   wtot[8];
  int2* buf = (int2*)sbuf4;

  const int g   = blockIdx.x;
  const int tid = threadIdx.x;
  if (tid < NBKT) cnt5[tid] = 0;

  // -- transpose sources [g*64, g*64+64): load half
  const int s0 = g * 64;
  {
    const int x = tid & 63, y = tid >> 6;       // y 0..15
    tile[x][y]      = spikes[(size_t)y        * S_ + s0 + x];
    tile[x][y + 16] = spikes[(size_t)(y + 16) * S_ + s0 + x];
  }

  // -- load my 4 edges (kept in registers across all phases)
  const int e4  = g * 1024 + tid;
  int4   t = reinterpret_cast<const int4*>(tgt)[e4];
  float4 a = reinterpret_cast<const float4*>(att)[e4];
  int4   d = reinterpret_cast<const int4*>(del)[e4];
  const int src = (e4 * 4) >> 6;                // 4 consecutive edges: 1 source

  __syncthreads();                              // cnt5 init + tile visible

  // -- transpose write
  {
    const int b = tid & 31, j = tid >> 5;       // j 0..31
    spikesT[(size_t)(s0 + j)      * 32 + b] = tile[j][b];
    spikesT[(size_t)(s0 + j + 32) * 32 + b] = tile[j + 32][b];
  }

  // -- pass 1: bucket histogram (ds_add, no return needed)
  const int bk0 = t.x >> 5, bk1 = t.y >> 5, bk2 = t.z >> 5, bk3 = t.w >> 5;
  __hip_atomic_fetch_add(&cnt5[bk0], 1, __ATOMIC_RELAXED, __HIP_MEMORY_SCOPE_WORKGROUP);
  __hip_atomic_fetch_add(&cnt5[bk1], 1, __ATOMIC_RELAXED, __HIP_MEMORY_SCOPE_WORKGROUP);
  __hip_atomic_fetch_add(&cnt5[bk2], 1, __ATOMIC_RELAXED, __HIP_MEMORY_SCOPE_WORKGROUP);
  __hip_atomic_fetch_add(&cnt5[bk3], 1, __ATOMIC_RELAXED, __HIP_MEMORY_SCOPE_WORKGROUP);
  __syncthreads();

  // -- exclusive scan of 512 bins: waves 0..7 shuffle-scan 64 each + combine
  int v = 0, incl = 0;
  if (tid < NBKT) {
    v = cnt5[tid];
    incl = v;
#pragma unroll
    for (int off = 1; off < 64; off <<= 1) {
      int u = __shfl_up(incl, off);
      if ((tid & 63) >= off) incl += u;
    }
    if ((tid & 63) == 63) wtot[tid >> 6] = incl;
  }
  __syncthreads();
  if (tid < NBKT) {
    int base = 0;
    const int wv = tid >> 6;
    for (int i = 0; i < wv; ++i) base += wtot[i];
    const int start = base + incl - v;
    sofs5[tid] = start;
    cur5[tid]  = start;
  }
  __syncthreads();

  // -- pass 2: weight + place into LDS at bucket cursor (exact, no overflow)
#define PUT(BK, TL, AV, DV)                                                   \
  {                                                                           \
    int p = __hip_atomic_fetch_add(&cur5[BK], 1, __ATOMIC_RELAXED,            \
                                   __HIP_MEMORY_SCOPE_WORKGROUP);             \
    buf[p] = make_int2(((TL) << 14) | src,                                    \
                       __float_as_int(edge_weight((AV), (DV))));              \
  }
  PUT(bk0, t.x & 31, a.x, d.x)
  PUT(bk1, t.y & 31, a.y, d.y)
  PUT(bk2, t.z & 31, a.z, d.z)
  PUT(bk3, t.w & 31, a.w, d.w)
#undef PUT
  __syncthreads();

  // -- flush: one contiguous 32 KB stream of full lines (int4 x2 per thread)
  int4* recO = reinterpret_cast<int4*>(rec) + (size_t)g * (EPG / 2);
  recO[tid]        = sbuf4[tid];
  recO[tid + 1024] = sbuf4[tid + 1024];
  if (tid < NBKT)
    ofse[(size_t)tid * GP_ + g] =          // transposed: column g, 4B stores
        ((unsigned)cur5[tid] << 16) | (unsigned)sofs5[tid];
}

// ---------------------------------------------------------------------------
// K2 (v11 = v8 + 8+8 gather interleave): fixed 128-slot per-target LDS
// slices, direct placement in pass 1 (no fine sort). Gather now keeps
// 16 srt reads + 16 spikesT loads outstanding (VGPR was 12-24: headroom),
// halving the serial dependent-batch count 16 -> 8. Third turn of the
// proven MLP crank (v4 +2us, v5 +2.3us).
__global__ __launch_bounds__(512) void consume(
    const int2*  __restrict__ rec,
    const unsigned int* __restrict__ ofse,
    const float* __restrict__ spikesT,
    float* __restrict__ out) {
  __shared__ int2  srt[TPB * CAPT];     // 32 KB, target t owns [t*CAPT, ...)
  __shared__ float otile[TPB][33];      // 4.2 KB
  __shared__ unsigned sse[GP_];         // 1 KB
  __shared__ int   cur32[TPB];
  __shared__ int2  ovf[OVF_CAP];
  __shared__ int   ovfn;

  const int k   = blockIdx.x;
  const int tid = threadIdx.x;
  const int b   = tid & 31;
  const int hw  = tid >> 5;             // 0..15

  if (tid < TPB) cur32[tid] = tid * CAPT;
  if (tid == 0)  ovfn = 0;
  if (tid < GP_) sse[tid] = ofse[(size_t)k * GP_ + tid];   // contiguous 1KB
  __syncthreads();

  // pass 1: 8 lanes per slice, 64 slices concurrent; direct placement.
  {
    const int grp = tid >> 3;           // 0..63
    const int l8  = tid & 7;
    for (int it = 0; it < 4; ++it) {
      const int g = grp + it * 64;
      const unsigned u = sse[g];
      const int st = (int)(u & 0xFFFF);
      const int n  = (int)(u >> 16) - st;
      const int2* slice = rec + (size_t)g * EPG + st;
      for (int j = l8; j < n; j += 8) {
        int2 r = slice[j];
        const int tl = (r.x >> 14) & 31;
        int p = __hip_atomic_fetch_add(&cur32[tl], 1, __ATOMIC_RELAXED,
                                       __HIP_MEMORY_SCOPE_WORKGROUP);
        if (p < (tl + 1) * CAPT) {
          srt[p] = r;
        } else {
          int q = __hip_atomic_fetch_add(&ovfn, 1, __ATOMIC_RELAXED,
                                         __HIP_MEMORY_SCOPE_WORKGROUP);
          if (q < OVF_CAP) ovf[q] = r;
        }
      }
    }
  }
  __syncthreads();

  // gather: half-wave hw owns targets hw (acc0) and hw+16 (acc1); lane=batch.
  // 8+8 interleave: 16 srt reads + 16 spikesT loads outstanding per batch.
  float acc0 = 0.f, acc1 = 0.f;
  int e0 = hw * CAPT;
  int e1 = (hw + 16) * CAPT;
  const int e0e = min(cur32[hw],      (hw + 1)  * CAPT);
  const int e1e = min(cur32[hw + 16], (hw + 17) * CAPT);

  for (; e0 + 8 <= e0e && e1 + 8 <= e1e; e0 += 8, e1 += 8) {
    int2 r0 = srt[e0], r1 = srt[e0 + 1], r2 = srt[e0 + 2], r3 = srt[e0 + 3];
    int2 r4 = srt[e0 + 4], r5 = srt[e0 + 5], r6 = srt[e0 + 6], r7 = srt[e0 + 7];
    int2 q0 = srt[e1], q1 = srt[e1 + 1], q2 = srt[e1 + 2], q3 = srt[e1 + 3];
    int2 q4 = srt[e1 + 4], q5 = srt[e1 + 5], q6 = srt[e1 + 6], q7 = srt[e1 + 7];
    float s0 = spikesT[(size_t)(r0.x & 0x3FFF) * 32 + b];
    float s1 = spikesT[(size_t)(r1.x & 0x3FFF) * 32 + b];
    float s2 = spikesT[(size_t)(r2.x & 0x3FFF) * 32 + b];
    float s3 = spikesT[(size_t)(r3.x & 0x3FFF) * 32 + b];
    float s4 = spikesT[(size_t)(r4.x & 0x3FFF) * 32 + b];
    float s5 = spikesT[(size_t)(r5.x & 0x3FFF) * 32 + b];
    float s6 = spikesT[(size_t)(r6.x & 0x3FFF) * 32 + b];
    float s7 = spikesT[(size_t)(r7.x & 0x3FFF) * 32 + b];
    float u0 = spikesT[(size_t)(q0.x & 0x3FFF) * 32 + b];
    float u1 = spikesT[(size_t)(q1.x & 0x3FFF) * 32 + b];
    float u2 = spikesT[(size_t)(q2.x & 0x3FFF) * 32 + b];
    float u3 = spikesT[(size_t)(q3.x & 0x3FFF) * 32 + b];
    float u4 = spikesT[(size_t)(q4.x & 0x3FFF) * 32 + b];
    float u5 = spikesT[(size_t)(q5.x & 0x3FFF) * 32 + b];
    float u6 = spikesT[(size_t)(q6.x & 0x3FFF) * 32 + b];
    float u7 = spikesT[(size_t)(q7.x & 0x3FFF) * 32 + b];
    acc0 = fmaf(__int_as_float(r0.y), s0, acc0);
    acc0 = fmaf(__int_as_float(r1.y), s1, acc0);
    acc0 = fmaf(__int_as_float(r2.y), s2, acc0);
    acc0 = fmaf(__int_as_float(r3.y), s3, acc0);
    acc0 = fmaf(__int_as_float(r4.y), s4, acc0);
    acc0 = fmaf(__int_as_float(r5.y), s5, acc0);
    acc0 = fmaf(__int_as_float(r6.y), s6, acc0);
    acc0 = fmaf(__int_as_float(r7.y), s7, acc0);
    acc1 = fmaf(__int_as_float(q0.y), u0, acc1);
    acc1 = fmaf(__int_as_float(q1.y), u1, acc1);
    acc1 = fmaf(__int_as_float(q2.y), u2, acc1);
    acc1 = fmaf(__int_as_float(q3.y), u3, acc1);
    acc1 = fmaf(__int_as_float(q4.y), u4, acc1);
    acc1 = fmaf(__int_as_float(q5.y), u5, acc1);
    acc1 = fmaf(__int_as_float(q6.y), u6, acc1);
    acc1 = fmaf(__int_as_float(q7.y), u7, acc1);
  }
  // 4+4 interleaved drain
  for (; e0 + 4 <= e0e && e1 + 4 <= e1e; e0 += 4, e1 += 4) {
    int2 r0 = srt[e0], r1 = srt[e0 + 1], r2 = srt[e0 + 2], r3 = srt[e0 + 3];
    int2 q0 = srt[e1], q1 = srt[e1 + 1], q2 = srt[e1 + 2], q3 = srt[e1 + 3];
    float s0 = spikesT[(size_t)(r0.x & 0x3FFF) * 32 + b];
    float s1 = spikesT[(size_t)(r1.x & 0x3FFF) * 32 + b];
    float s2 = spikesT[(size_t)(r2.x & 0x3FFF) * 32 + b];
    float s3 = spikesT[(size_t)(r3.x & 0x3FFF) * 32 + b];
    float u0 = spikesT[(size_t)(q0.x & 0x3FFF) * 32 + b];
    float u1 = spikesT[(size_t)(q1.x & 0x3FFF) * 32 + b];
    float u2 = spikesT[(size_t)(q2.x & 0x3FFF) * 32 + b];
    float u3 = spikesT[(size_t)(q3.x & 0x3FFF) * 32 + b];
    acc0 = fmaf(__int_as_float(r0.y), s0, acc0);
    acc0 = fmaf(__int_as_float(r1.y), s1, acc0);
    acc0 = fmaf(__int_as_float(r2.y), s2, acc0);
    acc0 = fmaf(__int_as_float(r3.y), s3, acc0);
    acc1 = fmaf(__int_as_float(q0.y), u0, acc1);
    acc1 = fmaf(__int_as_float(q1.y), u1, acc1);
    acc1 = fmaf(__int_as_float(q2.y), u2, acc1);
    acc1 = fmaf(__int_as_float(q3.y), u3, acc1);
  }
  // drain target A
  for (; e0 + 4 <= e0e; e0 += 4) {
    int2 r0 = srt[e0], r1 = srt[e0 + 1], r2 = srt[e0 + 2], r3 = srt[e0 + 3];
    float s0 = spikesT[(size_t)(r0.x & 0x3FFF) * 32 + b];
    float s1 = spikesT[(size_t)(r1.x & 0x3FFF) * 32 + b];
    float s2 = spikesT[(size_t)(r2.x & 0x3FFF) * 32 + b];
    float s3 = spikesT[(size_t)(r3.x & 0x3FFF) * 32 + b];
    acc0 = fmaf(__int_as_float(r0.y), s0, acc0);
    acc0 = fmaf(__int_as_float(r1.y), s1, acc0);
    acc0 = fmaf(__int_as_float(r2.y), s2, acc0);
    acc0 = fmaf(__int_as_float(r3.y), s3, acc0);
  }
  for (; e0 < e0e; ++e0) {
    int2 r = srt[e0];
    acc0 = fmaf(__int_as_float(r.y), spikesT[(size_t)(r.x & 0x3FFF) * 32 + b], acc0);
  }
  // drain target B
  for (; e1 + 4 <= e1e; e1 += 4) {
    int2 q0 = srt[e1], q1 = srt[e1 + 1], q2 = srt[e1 + 2], q3 = srt[e1 + 3];
    float u0 = spikesT[(size_t)(q0.x & 0x3FFF) * 32 + b];
    float u1 = spikesT[(size_t)(q1.x & 0x3FFF) * 32 + b];
    float u2 = spikesT[(size_t)(q2.x & 0x3FFF) * 32 + b];
    float u3 = spikesT[(size_t)(q3.x & 0x3FFF) * 32 + b];
    acc1 = fmaf(__int_as_float(q0.y), u0, acc1);
    acc1 = fmaf(__int_as_float(q1.y), u1, acc1);
    acc1 = fmaf(__int_as_float(q2.y), u2, acc1);
    acc1 = fmaf(__int_as_float(q3.y), u3, acc1);
  }
  for (; e1 < e1e; ++e1) {
    int2 q = srt[e1];
    acc1 = fmaf(__int_as_float(q.y), spikesT[(size_t)(q.x & 0x3FFF) * 32 + b], acc1);
  }

  // overflow drain (expected empty; correctness net for slice > CAPT)
  const int no = min(ovfn, OVF_CAP);
  for (int j = 0; j < no; ++j) {
    int2 r = ovf[j];
    const int tl = (r.x >> 14) & 31;
    float s = spikesT[(size_t)(r.x & 0x3FFF) * 32 + b];
    float w = __int_as_float(r.y);
    if (tl == hw)      acc0 = fmaf(w, s, acc0);
    if (tl == hw + 16) acc1 = fmaf(w, s, acc1);
  }

  // transpose 32x32 tile and write out coalesced
  otile[hw][b]      = acc0;
  otile[hw + 16][b] = acc1;
  __syncthreads();
  const int bb = tid >> 4;              // batch 0..31
  const int cc = (tid & 15) * 2;        // target pair
  float2 o2 = make_float2(otile[cc][bb], otile[cc + 1][bb]);
  *reinterpret_cast<float2*>(&out[(size_t)bb * T_ + k * 32 + cc]) = o2;
}

// ---------------------------------------------------------------------------
__global__ void zero_floats(float* __restrict__ p, int n) {
  int i = blockIdx.x * blockDim.x + threadIdx.x;
  if (i < n) p[i] = 0.0f;
}

// Emergency fallback (tiny ws): direct global atomics, weights inline.
__global__ void naive_kernel(const float* __restrict__ spikes,
                             const float* __restrict__ att,
                             const int*   __restrict__ tgt,
                             const int*   __restrict__ del,
                             float*       __restrict__ out) {
  int i = blockIdx.x * blockDim.x + threadIdx.x;
  if (i >= NEDGES) return;
  int   s = i >> 6;
  int   t = tgt[i];
  float w = edge_weight(att[i], del[i]);
  for (int b = 0; b < B_; ++b)
    unsafeAtomicAdd(&out[(size_t)b * T_ + t], w * spikes[(size_t)b * S_ + s]);
}

// ---------------------------------------------------------------------------
extern "C" void kernel_launch(void* const* d_in, const int* in_sizes, int n_in,
                              void* d_out, int out_size, void* d_ws, size_t ws_size,
                              hipStream_t stream) {
  const float* spikes = (const float*)d_in[0];
  const float* att    = (const float*)d_in[1];
  const int*   tgt    = (const int*)d_in[2];
  const int*   del    = (const int*)d_in[3];
  float*       out    = (float*)d_out;

  const size_t spikesT_bytes = (size_t)S_ * B_ * sizeof(float);         // 2 MB
  const size_t rec_bytes     = (size_t)NEDGES * sizeof(int2);           // 8 MB
  const size_t ofse_bytes    = (size_t)GP_ * NBKT * sizeof(unsigned);   // 512 KB
  const size_t need = spikesT_bytes + rec_bytes + ofse_bytes + 64;

  if (ws_size < need) {
    zero_floats<<<(B_ * T_ + 255) / 256, 256, 0, stream>>>(out, B_ * T_);
    naive_kernel<<<(NEDGES + 255) / 256, 256, 0, stream>>>(spikes, att, tgt, del, out);
    return;
  }

  char* p = (char*)d_ws;
  float*        spikesT = (float*)p;        p += spikesT_bytes;
  int2*         rec     = (int2*)p;         p += rec_bytes;
  unsigned int* ofse    = (unsigned int*)p;

  produce<<<GP_, 1024, 0, stream>>>(spikes, att, tgt, del, spikesT, rec, ofse);
  consume<<<NBKT, 512, 0, stream>>>(rec, ofse, spikesT, out);
}